// Round 4
// baseline (112.709 us; speedup 1.0000x reference)
//
#include <hip/hip_runtime.h>
#include <hip/hip_cooperative_groups.h>

namespace cg = cooperative_groups;

typedef unsigned short ushort_t;
typedef unsigned int   uint32;
typedef unsigned long long u64;
typedef __bf16 bf16_t;
typedef bf16_t bf16x8 __attribute__((ext_vector_type(8)));
typedef float  f32x4  __attribute__((ext_vector_type(4)));

#define N_TOK 4096
#define C_DIM 128
#define NTOT  8192
#define THRESH2 64.0f
#define NBLK 1024

// workspace layout (bytes)
#define XF_OFF  (0u)                      // bf16 [8192][128]  token-major xf (bf16)
#define YF_OFF  (2u<<20)                  // f32  [8192][128]  y
#define EF_OFF  (6u<<20)                  // (unused in coop path)
#define XE_OFF  (10u<<20)                 // f32  [8192][128]  xe
#define SQ_OFF  (14u<<20)                 // f32  [8192]
#define BN_OFF  ((14u<<20) + 32768u)      // f32  [8][256] partitioned bn partials
#define HB_OFF  (16u<<20)                 // u64  [8192][64] bitmask rows
#define WS_NEED ((size_t)(24u<<20))

__device__ __forceinline__ ushort_t f2b(float f){
    uint32 u = __float_as_uint(f);
    u += 0x7fffu + ((u>>16)&1u);
    return (ushort_t)(u>>16);
}
__device__ __forceinline__ u64 shfl_u64(u64 v, int src){
    uint32 lo = (uint32)v, hi = (uint32)(v>>32);
    lo = __shfl(lo, src); hi = __shfl(hi, src);
    return ((u64)hi<<32)|lo;
}
__device__ __forceinline__ u64 shfl_xor_u64(u64 v, int m){
    uint32 lo = (uint32)v, hi = (uint32)(v>>32);
    lo = __shfl_xor(lo, m); hi = __shfl_xor(hi, m);
    return ((u64)hi<<32)|lo;
}
__device__ __forceinline__ int wave_popc_reduce(u64 w){
    int cnt = __builtin_popcountll(w);
    cnt += __shfl_xor(cnt, 1);
    cnt += __shfl_xor(cnt, 2);
    cnt += __shfl_xor(cnt, 4);
    cnt += __shfl_xor(cnt, 8);
    cnt += __shfl_xor(cnt, 16);
    cnt += __shfl_xor(cnt, 32);
    return cnt;
}

// LDS union across phases: max = gram phase 37376 B -> 4 blocks/CU (149.5 KB of 160 KB)
union SMem {
    struct { ushort_t Xs[64*136]; ushort_t Ws[64*136]; } fc;                                 // 34816 B
    struct { ushort_t Al[64*136]; ushort_t Bl[64*136]; u64 rowW[64]; u64 part[256]; } gr;    // 37376 B
    struct { float r1[4][128]; float r2[4][128]; } agg;                                      // 4096 B
    struct { float tile[32][33]; } bn;                                                      // 4224 B
};

// ---------------- fused cooperative kernel v4 ----------------
// 1024 blocks x 256 threads, 4 blocks/CU. THREE grid.sync()s total.
// P1: FC (256 blocks); sync; P2: gram 64x64 (4160 items); sync;
// P3: TWO-HOP aggregation in one pass (Xe = Yf + D^-1 H D^-1 H Yf) + bn partials; sync;
// P4: BN affine + SiLU + transpose out.
__global__ __launch_bounds__(256, 4) void k_fused(const float* __restrict__ x,
                                                  const float* __restrict__ W,
                                                  const float* __restrict__ bfc,
                                                  const float* __restrict__ gamma,
                                                  const float* __restrict__ beta,
                                                  ushort_t* __restrict__ Xf,
                                                  float* __restrict__ Yf,
                                                  float* __restrict__ Ef,
                                                  float* __restrict__ Xe,
                                                  float* __restrict__ sq,
                                                  float* __restrict__ bnp,
                                                  u64* __restrict__ Hb,
                                                  float* __restrict__ out){
    __shared__ SMem sm;
    cg::grid_group grid = cg::this_grid();
    int tid = threadIdx.x;
    int bid = blockIdx.x;

    // ---------------- Phase 1: FC (fused transpose + MFMA + sq) ----------------
    if (bid < 256){
        int t0 = (bid >> 1) * 64;
        int dh = bid & 1;
        int b  = t0 >> 12;
        int n0 = t0 & 4095;
        if (bid == 0){
            #pragma unroll
            for (int k=0;k<8;k++) bnp[tid + 256*k] = 0.f;
        }
        const float* xb = x + (size_t)b * C_DIM * N_TOK + n0;
        #pragma unroll
        for (int k=0;k<8;k++){
            int idx = tid + 256*k;
            int c = idx >> 4, n4 = (idx & 15)*4;
            float4 v = *(const float4*)(xb + (size_t)c*N_TOK + n4);
            sm.fc.Xs[(n4+0)*136 + c] = f2b(v.x);
            sm.fc.Xs[(n4+1)*136 + c] = f2b(v.y);
            sm.fc.Xs[(n4+2)*136 + c] = f2b(v.z);
            sm.fc.Xs[(n4+3)*136 + c] = f2b(v.w);
        }
        const float* Wb = W + (size_t)dh*64*C_DIM;
        #pragma unroll
        for (int k=0;k<8;k++){
            int idx = tid + 256*k;
            int d = idx >> 5, c4 = (idx & 31)*4;
            float4 v = *(const float4*)(Wb + d*C_DIM + c4);
            uint2 u;
            u.x = (uint32)f2b(v.x) | ((uint32)f2b(v.y)<<16);
            u.y = (uint32)f2b(v.z) | ((uint32)f2b(v.w)<<16);
            *(uint2*)(&sm.fc.Ws[d*136 + c4]) = u;
        }
        __syncthreads();
        #pragma unroll
        for (int k=0;k<2;k++){
            int idx = tid + 256*(k + 2*dh);
            int row = idx >> 4, c8 = (idx & 15)*8;
            uint4 o = *(const uint4*)(&sm.fc.Xs[row*136 + c8]);
            *(uint4*)(Xf + (size_t)(t0 + row)*C_DIM + c8) = o;
        }
        if (dh == 0){
            int tok = tid >> 2, p = tid & 3;
            const ushort_t* xr = &sm.fc.Xs[tok*136 + p*32];
            float sacc = 0.f;
            #pragma unroll
            for (int i=0;i<16;i++){
                uint32 u = *(const uint32*)(&xr[i*2]);
                float v0 = __uint_as_float(u<<16);
                float v1 = __uint_as_float(u & 0xffff0000u);
                sacc = fmaf(v0, v0, sacc);
                sacc = fmaf(v1, v1, sacc);
            }
            sacc += __shfl_xor(sacc, 1);
            sacc += __shfl_xor(sacc, 2);
            if (p == 0) sq[t0 + tok] = sacc;
        }
        int wv = tid >> 6, lane = tid & 63;
        int qd = lane >> 4, m = lane & 15;
        f32x4 acc[4] = {{0,0,0,0},{0,0,0,0},{0,0,0,0},{0,0,0,0}};
        #pragma unroll
        for (int kc=0;kc<4;kc++){
            bf16x8 af = *(const bf16x8*)(&sm.fc.Xs[(wv*16 + m)*136 + kc*32 + qd*8]);
            #pragma unroll
            for (int ct=0;ct<4;ct++){
                bf16x8 bfr = *(const bf16x8*)(&sm.fc.Ws[(ct*16+m)*136 + kc*32 + qd*8]);
                acc[ct] = __builtin_amdgcn_mfma_f32_16x16x32_bf16(af, bfr, acc[ct], 0, 0, 0);
            }
        }
        int row = t0 + wv*16 + qd*4;
        #pragma unroll
        for (int ct=0;ct<4;ct++){
            int d = dh*64 + ct*16 + m;
            float bias = bfc[d];
            #pragma unroll
            for (int r=0;r<4;r++)
                Yf[(size_t)(row + r)*C_DIM + d] = acc[ct][r] + bias;
        }
    }
    grid.sync();

    // ---------------- Phase 2: symmetric Gram 64x64 -> H bitmask ----------------
    for (int item = bid; item < 4160; item += NBLK){
        __syncthreads();                   // protect LDS reuse across iterations
        int bb = (item >= 2080) ? 1 : 0;
        int L = item - bb*2080;
        // bi = largest i with i*(129-i)/2 <= L
        int bi = (int)((129.0f - sqrtf(16641.0f - 8.0f*(float)L)) * 0.5f);
        while (bi > 0 && bi*(129-bi)/2 > L) --bi;
        while ((bi+1)*(129-(bi+1))/2 <= L) ++bi;
        int bj = bi + (L - bi*(129-bi)/2);
        int i0 = bi*64, j0 = bj*64;
        const ushort_t* XfA = Xf + (size_t)(bb*N_TOK + i0)*C_DIM;
        const ushort_t* XfB = Xf + (size_t)(bb*N_TOK + j0)*C_DIM;
        #pragma unroll
        for (int k=0;k<4;k++){
            int q = tid + 256*k;            // 1024 x 16B : 64 rows
            int row = q >> 4, cp = (q & 15)*8;
            *(uint4*)(&sm.gr.Al[row*136 + cp]) = *(const uint4*)(XfA + row*C_DIM + cp);
            *(uint4*)(&sm.gr.Bl[row*136 + cp]) = *(const uint4*)(XfB + row*C_DIM + cp);
        }
        __syncthreads();
        int wv = tid >> 6, lane = tid & 63;
        int qd = lane >> 4, m = lane & 15;
        f32x4 acc[4] = {{0,0,0,0},{0,0,0,0},{0,0,0,0},{0,0,0,0}};
        #pragma unroll
        for (int kc=0;kc<4;kc++){
            bf16x8 a0 = *(const bf16x8*)(&sm.gr.Al[(wv*16 + m)*136 + kc*32 + qd*8]);
            #pragma unroll
            for (int ct=0;ct<4;ct++){
                bf16x8 bfr = *(const bf16x8*)(&sm.gr.Bl[(ct*16+m)*136 + kc*32 + qd*8]);
                acc[ct] = __builtin_amdgcn_mfma_f32_16x16x32_bf16(a0, bfr, acc[ct], 0, 0, 0);
            }
        }
        float sqj[4];
        #pragma unroll
        for (int ct=0;ct<4;ct++) sqj[ct] = sq[bb*N_TOK + j0 + ct*16 + m];
        int lr = wv*16 + qd*4;
        int ib = i0 + lr;
        float sqi[4];
        #pragma unroll
        for (int r=0;r<4;r++) sqi[r] = sq[bb*N_TOK + ib + r];
        #pragma unroll
        for (int r=0;r<4;r++){
            u64 bits = 0;
            #pragma unroll
            for (int ct=0;ct<4;ct++){
                float d2 = sqi[r] + sqj[ct] - 2.0f*acc[ct][r];
                if (d2 < THRESH2) bits |= (u64)1 << (ct*16 + m);
            }
            bits |= shfl_xor_u64(bits, 1);
            bits |= shfl_xor_u64(bits, 2);
            bits |= shfl_xor_u64(bits, 4);
            bits |= shfl_xor_u64(bits, 8);
            if (m == 0){
                Hb[(size_t)(bb*N_TOK + ib + r)*64 + bj] = bits;
                sm.gr.rowW[lr + r] = bits;
            }
        }
        __syncthreads();
        if (bi != bj){   // mirror write (bit-transposed); diagonal covered by straight
            int jj = tid & 63, q = tid >> 6;
            u64 p = 0;
            int ibase = q*16;
            #pragma unroll
            for (int ii=0; ii<16; ii++)
                p |= ((sm.gr.rowW[ibase + ii] >> jj) & 1ull) << (ibase + ii);
            sm.gr.part[tid] = p;
            __syncthreads();
            if (tid < 64){
                u64 wt = sm.gr.part[tid] | sm.gr.part[tid+64] | sm.gr.part[tid+128] | sm.gr.part[tid+192];
                Hb[(size_t)(bb*N_TOK + j0 + tid)*64 + bi] = wt;
            }
        }
    }
    grid.sync();

    // ---------------- Phase 3: TWO-HOP aggregation, single pass ----------------
    // Xe_i = Yf_i + nrm_i * sum_{j in N(i)} nrm_j * sum_{k in N(j)} Yf_k
    // (H bitwise symmetric; j==i fast path reuses the row mask/degree.)
    {
        int wv = tid >> 6, lane = tid & 63;
        float s1a=0.f, s1b=0.f, s2a=0.f, s2b=0.f;
        #pragma unroll
        for (int k=0;k<2;k++){
            int row = (bid + k*NBLK)*4 + wv;      // [0, 8192)
            int b = row >> 12;
            const float* Vb = Yf + (size_t)b*N_TOK*C_DIM;
            u64 myw = Hb[(size_t)row*64 + lane];
            int cnt = wave_popc_reduce(myw);
            float nrm_i = (cnt > 0) ? 1.0f/(float)cnt : 0.0f;
            float acc0 = 0.f, acc1 = 0.f;
            u64 nz = __ballot(myw != 0);
            while (nz){
                int wdi = __builtin_ctzll(nz);
                nz &= nz - 1;
                u64 mw = shfl_u64(myw, wdi);
                while (mw){
                    int j = wdi*64 + __builtin_ctzll(mw);   // local token in batch
                    mw &= mw - 1;
                    int jrow = (b << 12) + j;
                    u64 jw; float nrm_j;
                    if (jrow == row){                        // dominant diagonal case
                        jw = myw; nrm_j = nrm_i;
                    } else {
                        jw = Hb[(size_t)jrow*64 + lane];
                        int jc = wave_popc_reduce(jw);
                        nrm_j = (jc > 0) ? 1.0f/(float)jc : 0.0f;
                    }
                    float sub0 = 0.f, sub1 = 0.f;
                    u64 jnz = __ballot(jw != 0);
                    while (jnz){
                        int w2 = __builtin_ctzll(jnz);
                        jnz &= jnz - 1;
                        u64 m2 = shfl_u64(jw, w2);
                        while (m2){
                            int kk = w2*64 + __builtin_ctzll(m2);
                            m2 &= m2 - 1;
                            sub0 += Vb[(size_t)kk*C_DIM + lane];
                            sub1 += Vb[(size_t)kk*C_DIM + lane + 64];
                        }
                    }
                    acc0 += nrm_j * sub0;
                    acc1 += nrm_j * sub1;
                }
            }
            size_t o = (size_t)row*C_DIM;
            float xe0 = Yf[o + lane]      + nrm_i*acc0;
            float xe1 = Yf[o + lane + 64] + nrm_i*acc1;
            Xe[o + lane]      = xe0;
            Xe[o + lane + 64] = xe1;
            s1a += xe0; s2a += xe0*xe0;
            s1b += xe1; s2b += xe1*xe1;
        }
        __syncthreads();                   // LDS handoff from phase 2
        sm.agg.r1[wv][lane]      = s1a;
        sm.agg.r1[wv][lane + 64] = s1b;
        sm.agg.r2[wv][lane]      = s2a;
        sm.agg.r2[wv][lane + 64] = s2b;
        __syncthreads();
        if (tid < 128){
            float s1 = sm.agg.r1[0][tid]+sm.agg.r1[1][tid]+sm.agg.r1[2][tid]+sm.agg.r1[3][tid];
            float s2 = sm.agg.r2[0][tid]+sm.agg.r2[1][tid]+sm.agg.r2[2][tid]+sm.agg.r2[3][tid];
            int prt = bid & 7;
            atomicAdd(&bnp[prt*256 + tid],       s1);
            atomicAdd(&bnp[prt*256 + 128 + tid], s2);
        }
    }
    grid.sync();

    // ---------------- Phase 4: BN affine + SiLU + transpose out ----------------
    {
        int it = bid;
        int bx = it & 127, byz = it >> 7;
        int by = byz & 3, bz = byz >> 2;
        int tx = tid & 31, ty = tid >> 5;
        int n0 = bx*32, c0 = by*32, b = bz;
        int c = c0 + tx;
        float s1 = 0.f, s2 = 0.f;
        #pragma unroll
        for (int p=0;p<8;p++){
            s1 += bnp[p*256 + c];
            s2 += bnp[p*256 + 128 + c];
        }
        float inv = 1.0f / (float)NTOT;
        float mean = s1 * inv;
        float var  = s2*inv - mean*mean;
        float scale = gamma[c] * rsqrtf(var + 1e-5f);
        float shift = beta[c] - mean*scale;
        #pragma unroll
        for (int k=0;k<4;k++){
            int nl = ty + 8*k;
            float v = Xe[(size_t)(b*N_TOK + n0 + nl)*C_DIM + c];
            v = scale*v + shift;
            float sg = 1.0f/(1.0f + __expf(-v));
            sm.bn.tile[tx][nl] = v * sg;
        }
        __syncthreads();
        #pragma unroll
        for (int k=0;k<4;k++){
            int cl = ty + 8*k;
            out[(size_t)(b*C_DIM + c0 + cl)*N_TOK + n0 + tx] = sm.bn.tile[cl][tx];
        }
    }
}

// ================= fallback path: original 5 kernels (unchanged) =================
__global__ __launch_bounds__(256) void k_fc(const float* __restrict__ x,
                                            const float* __restrict__ W,
                                            const float* __restrict__ bfc,
                                            ushort_t* __restrict__ Xf,
                                            float* __restrict__ Yf,
                                            float* __restrict__ sq,
                                            float* __restrict__ bnp){
    __shared__ ushort_t Xs[64*136];
    __shared__ ushort_t Ws[64*136];
    int tid = threadIdx.x;
    int t0 = blockIdx.x * 64;
    int dh = blockIdx.y;
    int b  = t0 >> 12;
    int n0 = t0 & 4095;
    if (blockIdx.x == 0 && dh == 0){
        #pragma unroll
        for (int k=0;k<8;k++) bnp[tid + 256*k] = 0.f;
    }
    const float* xb = x + (size_t)b * C_DIM * N_TOK + n0;
    #pragma unroll
    for (int k=0;k<8;k++){
        int idx = tid + 256*k;
        int c = idx >> 4, n4 = (idx & 15)*4;
        float4 v = *(const float4*)(xb + (size_t)c*N_TOK + n4);
        Xs[(n4+0)*136 + c] = f2b(v.x);
        Xs[(n4+1)*136 + c] = f2b(v.y);
        Xs[(n4+2)*136 + c] = f2b(v.z);
        Xs[(n4+3)*136 + c] = f2b(v.w);
    }
    const float* Wb = W + (size_t)dh*64*C_DIM;
    #pragma unroll
    for (int k=0;k<8;k++){
        int idx = tid + 256*k;
        int d = idx >> 5, c4 = (idx & 31)*4;
        float4 v = *(const float4*)(Wb + d*C_DIM + c4);
        uint2 u;
        u.x = (uint32)f2b(v.x) | ((uint32)f2b(v.y)<<16);
        u.y = (uint32)f2b(v.z) | ((uint32)f2b(v.w)<<16);
        *(uint2*)(&Ws[d*136 + c4]) = u;
    }
    __syncthreads();
    #pragma unroll
    for (int k=0;k<2;k++){
        int idx = tid + 256*(k + 2*dh);
        int row = idx >> 4, c8 = (idx & 15)*8;
        uint4 o = *(const uint4*)(&Xs[row*136 + c8]);
        *(uint4*)(Xf + (size_t)(t0 + row)*C_DIM + c8) = o;
    }
    if (dh == 0){
        int tok = tid >> 2, p = tid & 3;
        const ushort_t* xr = &Xs[tok*136 + p*32];
        float sacc = 0.f;
        #pragma unroll
        for (int i=0;i<16;i++){
            uint32 u = *(const uint32*)(&xr[i*2]);
            float v0 = __uint_as_float(u<<16);
            float v1 = __uint_as_float(u & 0xffff0000u);
            sacc = fmaf(v0, v0, sacc);
            sacc = fmaf(v1, v1, sacc);
        }
        sacc += __shfl_xor(sacc, 1);
        sacc += __shfl_xor(sacc, 2);
        if (p == 0) sq[t0 + tok] = sacc;
    }
    int wv = tid >> 6, lane = tid & 63;
    int qd = lane >> 4, m = lane & 15;
    f32x4 acc[4] = {{0,0,0,0},{0,0,0,0},{0,0,0,0},{0,0,0,0}};
    #pragma unroll
    for (int kc=0;kc<4;kc++){
        bf16x8 af = *(const bf16x8*)(&Xs[(wv*16 + m)*136 + kc*32 + qd*8]);
        #pragma unroll
        for (int ct=0;ct<4;ct++){
            bf16x8 bfr = *(const bf16x8*)(&Ws[(ct*16+m)*136 + kc*32 + qd*8]);
            acc[ct] = __builtin_amdgcn_mfma_f32_16x16x32_bf16(af, bfr, acc[ct], 0, 0, 0);
        }
    }
    int row = t0 + wv*16 + qd*4;
    #pragma unroll
    for (int ct=0;ct<4;ct++){
        int d = dh*64 + ct*16 + m;
        float bias = bfc[d];
        #pragma unroll
        for (int r=0;r<4;r++)
            Yf[(size_t)(row + r)*C_DIM + d] = acc[ct][r] + bias;
    }
}

__global__ __launch_bounds__(256) void k_gram(const ushort_t* __restrict__ Xf,
                                              const float* __restrict__ sq,
                                              u64* __restrict__ Hb){
    __shared__ ushort_t Al[128*136];
    __shared__ ushort_t Bl[64*136];
    __shared__ u64 rowW[128];
    __shared__ u64 part[256];
    int tid = threadIdx.x;
    int L = blockIdx.x, b = blockIdx.y;
    int bi = (int)((65.0f - sqrtf(4225.0f - 4.0f*(float)L)) * 0.5f);
    while (bi > 0 && bi*(65-bi) > L) --bi;
    while ((bi+1)*(65-(bi+1)) <= L) ++bi;
    int bj = L - bi*(65-bi) + 2*bi;
    int i0 = bi*128, j0 = bj*64;
    const ushort_t* XfA = Xf + (size_t)(b*N_TOK + i0)*C_DIM;
    const ushort_t* XfB = Xf + (size_t)(b*N_TOK + j0)*C_DIM;
    #pragma unroll
    for (int k=0;k<8;k++){
        int q = tid + 256*k;
        int row = q >> 4, cp = (q & 15)*8;
        *(uint4*)(&Al[row*136 + cp]) = *(const uint4*)(XfA + row*C_DIM + cp);
    }
    #pragma unroll
    for (int k=0;k<4;k++){
        int q = tid + 256*k;
        int row = q >> 4, cp = (q & 15)*8;
        *(uint4*)(&Bl[row*136 + cp]) = *(const uint4*)(XfB + row*C_DIM + cp);
    }
    __syncthreads();
    int wv = tid >> 6, lane = tid & 63;
    int qd = lane >> 4, m = lane & 15;
    f32x4 acc[2][4] = {{{0,0,0,0},{0,0,0,0},{0,0,0,0},{0,0,0,0}},
                       {{0,0,0,0},{0,0,0,0},{0,0,0,0},{0,0,0,0}}};
    #pragma unroll
    for (int kc=0;kc<4;kc++){
        bf16x8 a0 = *(const bf16x8*)(&Al[(wv*32 +      m)*136 + kc*32 + qd*8]);
        bf16x8 a1 = *(const bf16x8*)(&Al[(wv*32 + 16 + m)*136 + kc*32 + qd*8]);
        #pragma unroll
        for (int ct=0;ct<4;ct++){
            bf16x8 bfr = *(const bf16x8*)(&Bl[(ct*16+m)*136 + kc*32 + qd*8]);
            acc[0][ct] = __builtin_amdgcn_mfma_f32_16x16x32_bf16(a0, bfr, acc[0][ct], 0, 0, 0);
            acc[1][ct] = __builtin_amdgcn_mfma_f32_16x16x32_bf16(a1, bfr, acc[1][ct], 0, 0, 0);
        }
    }
    float sqj[4];
    #pragma unroll
    for (int ct=0;ct<4;ct++) sqj[ct] = sq[b*N_TOK + j0 + ct*16 + m];
    #pragma unroll
    for (int rt=0;rt<2;rt++){
        int lr = wv*32 + rt*16 + qd*4;
        int ib = i0 + lr;
        float sqi[4];
        #pragma unroll
        for (int r=0;r<4;r++) sqi[r] = sq[b*N_TOK + ib + r];
        #pragma unroll
        for (int r=0;r<4;r++){
            u64 bits = 0;
            #pragma unroll
            for (int ct=0;ct<4;ct++){
                float d2 = sqi[r] + sqj[ct] - 2.0f*acc[rt][ct][r];
                if (d2 < THRESH2) bits |= (u64)1 << (ct*16 + m);
            }
            bits |= shfl_xor_u64(bits, 1);
            bits |= shfl_xor_u64(bits, 2);
            bits |= shfl_xor_u64(bits, 4);
            bits |= shfl_xor_u64(bits, 8);
            if (m == 0){
                Hb[(size_t)(b*N_TOK + ib + r)*64 + bj] = bits;
                rowW[lr + r] = bits;
            }
        }
    }
    __syncthreads();
    {
        int jj = tid & 63, hw = (tid>>6)&1, sub = tid>>7;
        u64 p = 0;
        int ibase = hw*64 + sub*32;
        #pragma unroll 8
        for (int ii=0; ii<32; ii++){
            u64 wrd = rowW[ibase + ii];
            p |= ((wrd >> jj) & 1ull) << (sub*32 + ii);
        }
        part[tid] = p;
    }
    __syncthreads();
    if (tid < 128){
        int jj = tid & 63, hw = tid >> 6;
        u64 wt = part[tid] | part[tid + 128];
        Hb[(size_t)(b*N_TOK + j0 + jj)*64 + 2*bi + hw] = wt;
    }
}

template<int MODE>
__global__ __launch_bounds__(256) void k_aggs(const u64* __restrict__ Hb,
                                              const float* __restrict__ V,
                                              const float* __restrict__ Yf,
                                              float* __restrict__ Out,
                                              float* __restrict__ bnp){
    __shared__ float r1[4][128];
    __shared__ float r2[4][128];
    int tid = threadIdx.x;
    int wv = tid >> 6, lane = tid & 63;
    int row = blockIdx.x * 4 + wv;
    int b = row >> 12;
    u64 myw = Hb[(size_t)row*64 + lane];
    int cnt = __builtin_popcountll(myw);
    cnt += __shfl_xor(cnt, 1);
    cnt += __shfl_xor(cnt, 2);
    cnt += __shfl_xor(cnt, 4);
    cnt += __shfl_xor(cnt, 8);
    cnt += __shfl_xor(cnt, 16);
    cnt += __shfl_xor(cnt, 32);
    float acc0 = 0.f, acc1 = 0.f;
    const float* Vb = V + (size_t)b*N_TOK*C_DIM;
    u64 nz = __ballot(myw != 0);
    while (nz){
        int wdi = __builtin_ctzll(nz);
        nz &= nz - 1;
        u64 mw = shfl_u64(myw, wdi);
        while (mw){
            int j = wdi*64 + __builtin_ctzll(mw);
            mw &= mw - 1;
            acc0 += Vb[(size_t)j*C_DIM + lane];
            acc1 += Vb[(size_t)j*C_DIM + lane + 64];
        }
    }
    float norm = (cnt > 0) ? (1.0f/(float)cnt) : 0.0f;
    size_t o = (size_t)row*C_DIM;
    if (MODE == 0){
        Out[o + lane]      = acc0*norm;
        Out[o + lane + 64] = acc1*norm;
    } else {
        float xe0 = Yf[o + lane]      + acc0*norm;
        float xe1 = Yf[o + lane + 64] + acc1*norm;
        Out[o + lane]      = xe0;
        Out[o + lane + 64] = xe1;
        r1[wv][lane]      = xe0;
        r1[wv][lane + 64] = xe1;
        r2[wv][lane]      = xe0*xe0;
        r2[wv][lane + 64] = xe1*xe1;
        __syncthreads();
        if (tid < 128){
            float s1 = r1[0][tid]+r1[1][tid]+r1[2][tid]+r1[3][tid];
            float s2 = r2[0][tid]+r2[1][tid]+r2[2][tid]+r2[3][tid];
            int prt = blockIdx.x & 7;
            atomicAdd(&bnp[prt*256 + tid],       s1);
            atomicAdd(&bnp[prt*256 + 128 + tid], s2);
        }
    }
}

__global__ __launch_bounds__(256) void k_out(const float* __restrict__ Xe,
                                             const float* __restrict__ bnp,
                                             const float* __restrict__ gamma,
                                             const float* __restrict__ beta,
                                             float* __restrict__ out){
    __shared__ float tile[32][33];
    int tx = threadIdx.x, ty = threadIdx.y;
    int n0 = blockIdx.x*32, c0 = blockIdx.y*32, b = blockIdx.z;
    int c = c0 + tx;
    float s1 = 0.f, s2 = 0.f;
    #pragma unroll
    for (int p=0;p<8;p++){
        s1 += bnp[p*256 + c];
        s2 += bnp[p*256 + 128 + c];
    }
    float inv = 1.0f / (float)NTOT;
    float mean = s1 * inv;
    float var  = s2*inv - mean*mean;
    float scale = gamma[c] * rsqrtf(var + 1e-5f);
    float shift = beta[c] - mean*scale;
    #pragma unroll
    for (int k=0;k<4;k++){
        int nl = ty + 8*k;
        float v = Xe[(size_t)(b*N_TOK + n0 + nl)*C_DIM + c];
        v = scale*v + shift;
        float sg = 1.0f/(1.0f + __expf(-v));
        tile[tx][nl] = v * sg;
    }
    __syncthreads();
    #pragma unroll
    for (int k=0;k<4;k++){
        int cl = ty + 8*k;
        out[(size_t)(b*C_DIM + c0 + cl)*N_TOK + n0 + tx] = tile[cl][tx];
    }
}

extern "C" void kernel_launch(void* const* d_in, const int* in_sizes, int n_in,
                              void* d_out, int out_size, void* d_ws, size_t ws_size,
                              hipStream_t stream){
    if (ws_size < WS_NEED) return;
    const float* x     = (const float*)d_in[0];
    const float* W     = (const float*)d_in[1];
    const float* bfc   = (const float*)d_in[2];
    const float* gamma = (const float*)d_in[3];
    const float* beta  = (const float*)d_in[4];
    char* ws = (char*)d_ws;
    ushort_t* Xf = (ushort_t*)(ws + XF_OFF);
    float*    Yf = (float*)(ws + YF_OFF);
    float*    Ef = (float*)(ws + EF_OFF);
    float*    Xe = (float*)(ws + XE_OFF);
    float*    sqp= (float*)(ws + SQ_OFF);
    float*    bnp= (float*)(ws + BN_OFF);
    u64*      Hb = (u64*)(ws + HB_OFF);
    float*    outp = (float*)d_out;

    // one-time check: can the fused kernel run cooperatively at NBLK blocks?
    static int coop_ok = -1;
    if (coop_ok < 0){
        int ok = 0, dev = 0, nb = 0;
        if (hipGetDevice(&dev) == hipSuccess){
            hipDeviceProp_t prop;
            if (hipGetDeviceProperties(&prop, dev) == hipSuccess &&
                hipOccupancyMaxActiveBlocksPerMultiprocessor(&nb, (const void*)k_fused, 256, 0) == hipSuccess){
                ok = (prop.cooperativeLaunch != 0) && (nb * prop.multiProcessorCount >= NBLK);
            }
        }
        coop_ok = ok;
    }

    if (coop_ok){
        void* args[] = {(void*)&x, (void*)&W, (void*)&bfc, (void*)&gamma, (void*)&beta,
                        (void*)&Xf, (void*)&Yf, (void*)&Ef, (void*)&Xe, (void*)&sqp,
                        (void*)&bnp, (void*)&Hb, (void*)&outp};
        hipError_t e = hipLaunchCooperativeKernel((const void*)k_fused, dim3(NBLK), dim3(256),
                                                  args, 0, stream);
        if (e == hipSuccess) return;
        // fall through to the 5-kernel path on failure
    }

    k_fc<<<dim3(128,2), dim3(256), 0, stream>>>(x, W, bfc, Xf, Yf, sqp, bnp);
    k_gram<<<dim3(1056,2), dim3(256), 0, stream>>>(Xf, sqp, Hb);
    k_aggs<0><<<dim3(2048), dim3(256), 0, stream>>>(Hb, Yf, Yf, Ef, bnp);
    k_aggs<1><<<dim3(2048), dim3(256), 0, stream>>>(Hb, Ef, Yf, Xe, bnp);
    k_out<<<dim3(128,4,2), dim3(32,8), 0, stream>>>(Xe, bnp, gamma, beta, outp);
}

// Round 5
// 103.267 us; speedup vs baseline: 1.0914x; 1.0914x over previous
//
#include <hip/hip_runtime.h>

typedef unsigned short ushort_t;
typedef unsigned int   uint32;
typedef unsigned long long u64;
typedef __bf16 bf16_t;
typedef bf16_t bf16x8 __attribute__((ext_vector_type(8)));
typedef float  f32x4  __attribute__((ext_vector_type(4)));

#define N_TOK 4096
#define C_DIM 128
#define NTOT  8192
#define THRESH2 64.0f

// workspace layout (bytes)
#define XF_OFF  (0u)                      // bf16 [8192][128]  token-major xf (bf16)
#define YF_OFF  (2u<<20)                  // f32  [8192][128]  y
#define XE_OFF  (10u<<20)                 // f32  [8192][128]  xe
#define SQ_OFF  (14u<<20)                 // f32  [8192]
#define BN_OFF  ((14u<<20) + 32768u)      // f32  [8][256] partitioned bn partials
#define HB_OFF  (16u<<20)                 // u64  [8192][64] bitmask rows
#define WS_NEED ((size_t)(24u<<20))

__device__ __forceinline__ ushort_t f2b(float f){
    uint32 u = __float_as_uint(f);
    u += 0x7fffu + ((u>>16)&1u);
    return (ushort_t)(u>>16);
}
__device__ __forceinline__ u64 shfl_u64(u64 v, int src){
    uint32 lo = (uint32)v, hi = (uint32)(v>>32);
    lo = __shfl(lo, src); hi = __shfl(hi, src);
    return ((u64)hi<<32)|lo;
}
__device__ __forceinline__ u64 shfl_xor_u64(u64 v, int m){
    uint32 lo = (uint32)v, hi = (uint32)(v>>32);
    lo = __shfl_xor(lo, m); hi = __shfl_xor(hi, m);
    return ((u64)hi<<32)|lo;
}
__device__ __forceinline__ int wave_popc_reduce(u64 w){
    int cnt = __builtin_popcountll(w);
    cnt += __shfl_xor(cnt, 1);
    cnt += __shfl_xor(cnt, 2);
    cnt += __shfl_xor(cnt, 4);
    cnt += __shfl_xor(cnt, 8);
    cnt += __shfl_xor(cnt, 16);
    cnt += __shfl_xor(cnt, 32);
    return cnt;
}

// K1: fused transpose + FC (MFMA) + sq. Grid (128 token-groups, 2 d-halves).
__global__ __launch_bounds__(256) void k_fc(const float* __restrict__ x,
                                            const float* __restrict__ W,
                                            const float* __restrict__ bfc,
                                            ushort_t* __restrict__ Xf,
                                            float* __restrict__ Yf,
                                            float* __restrict__ sq,
                                            float* __restrict__ bnp){
    __shared__ ushort_t Xs[64*136];    // 64 tokens x 128 c (stride 136)
    __shared__ ushort_t Ws[64*136];    // 64 d x 128 c
    int tid = threadIdx.x;
    int t0 = blockIdx.x * 64;          // flat token base (0..8191)
    int dh = blockIdx.y;               // d-half
    int b  = t0 >> 12;
    int n0 = t0 & 4095;
    if (blockIdx.x == 0 && dh == 0){
        #pragma unroll
        for (int k=0;k<8;k++) bnp[tid + 256*k] = 0.f;
    }
    const float* xb = x + (size_t)b * C_DIM * N_TOK + n0;
    #pragma unroll
    for (int k=0;k<8;k++){
        int idx = tid + 256*k;         // 2048 float4s = 64 n x 128 c
        int c = idx >> 4, n4 = (idx & 15)*4;
        float4 v = *(const float4*)(xb + (size_t)c*N_TOK + n4);
        Xs[(n4+0)*136 + c] = f2b(v.x);
        Xs[(n4+1)*136 + c] = f2b(v.y);
        Xs[(n4+2)*136 + c] = f2b(v.z);
        Xs[(n4+3)*136 + c] = f2b(v.w);
    }
    const float* Wb = W + (size_t)dh*64*C_DIM;
    #pragma unroll
    for (int k=0;k<8;k++){
        int idx = tid + 256*k;         // 2048 float4s = 64 d x 128 c
        int d = idx >> 5, c4 = (idx & 31)*4;
        float4 v = *(const float4*)(Wb + d*C_DIM + c4);
        uint2 u;
        u.x = (uint32)f2b(v.x) | ((uint32)f2b(v.y)<<16);
        u.y = (uint32)f2b(v.z) | ((uint32)f2b(v.w)<<16);
        *(uint2*)(&Ws[d*136 + c4]) = u;
    }
    __syncthreads();
    // write Xf rows [dh*32, dh*32+32) (coalesced 16B)
    #pragma unroll
    for (int k=0;k<2;k++){
        int idx = tid + 256*(k + 2*dh);
        int row = idx >> 4, c8 = (idx & 15)*8;
        uint4 o = *(const uint4*)(&Xs[row*136 + c8]);
        *(uint4*)(Xf + (size_t)(t0 + row)*C_DIM + c8) = o;
    }
    // sq[token] = sum_c xf^2 (dh==0 only)
    if (dh == 0){
        int tok = tid >> 2, p = tid & 3;
        const ushort_t* xr = &Xs[tok*136 + p*32];
        float sacc = 0.f;
        #pragma unroll
        for (int i=0;i<16;i++){
            uint32 u = *(const uint32*)(&xr[i*2]);
            float v0 = __uint_as_float(u<<16);
            float v1 = __uint_as_float(u & 0xffff0000u);
            sacc = fmaf(v0, v0, sacc);
            sacc = fmaf(v1, v1, sacc);
        }
        sacc += __shfl_xor(sacc, 1);
        sacc += __shfl_xor(sacc, 2);
        if (p == 0) sq[t0 + tok] = sacc;
    }
    // MFMA: y[tok][dh*64 + d] = sum_c Xs[tok][c] * Ws[d][c]
    int wv = tid >> 6, lane = tid & 63;
    int qd = lane >> 4, m = lane & 15;
    f32x4 acc[4] = {{0,0,0,0},{0,0,0,0},{0,0,0,0},{0,0,0,0}};
    #pragma unroll
    for (int kc=0;kc<4;kc++){
        bf16x8 af = *(const bf16x8*)(&Xs[(wv*16 + m)*136 + kc*32 + qd*8]);
        #pragma unroll
        for (int ct=0;ct<4;ct++){
            bf16x8 bfr = *(const bf16x8*)(&Ws[(ct*16+m)*136 + kc*32 + qd*8]);
            acc[ct] = __builtin_amdgcn_mfma_f32_16x16x32_bf16(af, bfr, acc[ct], 0, 0, 0);
        }
    }
    int row = t0 + wv*16 + qd*4;
    #pragma unroll
    for (int ct=0;ct<4;ct++){
        int d = dh*64 + ct*16 + m;
        float bias = bfc[d];
        #pragma unroll
        for (int r=0;r<4;r++)
            Yf[(size_t)(row + r)*C_DIM + d] = acc[ct][r] + bias;
    }
}

// K2: symmetric Gram, 64x64 tiles, upper triangle incl. diagonal.
// 2080 tiles per batch; mirror written via in-LDS bit-transpose.
// LDS 37376 B -> 4 blocks/CU. (Numerics proven in coop rounds 3/4.)
__global__ __launch_bounds__(256) void k_gram64(const ushort_t* __restrict__ Xf,
                                                const float* __restrict__ sq,
                                                u64* __restrict__ Hb){
    __shared__ ushort_t Al[64*136];
    __shared__ ushort_t Bl[64*136];
    __shared__ u64 rowW[64];
    __shared__ u64 part[256];
    int tid = threadIdx.x;
    int L = blockIdx.x, bb = blockIdx.y;
    // bi = largest i with i*(129-i)/2 <= L
    int bi = (int)((129.0f - sqrtf(16641.0f - 8.0f*(float)L)) * 0.5f);
    while (bi > 0 && bi*(129-bi)/2 > L) --bi;
    while ((bi+1)*(129-(bi+1))/2 <= L) ++bi;
    int bj = bi + (L - bi*(129-bi)/2);
    int i0 = bi*64, j0 = bj*64;
    const ushort_t* XfA = Xf + (size_t)(bb*N_TOK + i0)*C_DIM;
    const ushort_t* XfB = Xf + (size_t)(bb*N_TOK + j0)*C_DIM;
    #pragma unroll
    for (int k=0;k<4;k++){
        int q = tid + 256*k;            // 1024 x 16B : 64 rows x 128 c
        int row = q >> 4, cp = (q & 15)*8;
        *(uint4*)(&Al[row*136 + cp]) = *(const uint4*)(XfA + row*C_DIM + cp);
        *(uint4*)(&Bl[row*136 + cp]) = *(const uint4*)(XfB + row*C_DIM + cp);
    }
    __syncthreads();
    int wv = tid >> 6, lane = tid & 63;
    int qd = lane >> 4, m = lane & 15;
    f32x4 acc[4] = {{0,0,0,0},{0,0,0,0},{0,0,0,0},{0,0,0,0}};
    #pragma unroll
    for (int kc=0;kc<4;kc++){
        bf16x8 a0 = *(const bf16x8*)(&Al[(wv*16 + m)*136 + kc*32 + qd*8]);
        #pragma unroll
        for (int ct=0;ct<4;ct++){
            bf16x8 bfr = *(const bf16x8*)(&Bl[(ct*16+m)*136 + kc*32 + qd*8]);
            acc[ct] = __builtin_amdgcn_mfma_f32_16x16x32_bf16(a0, bfr, acc[ct], 0, 0, 0);
        }
    }
    float sqj[4];
    #pragma unroll
    for (int ct=0;ct<4;ct++) sqj[ct] = sq[bb*N_TOK + j0 + ct*16 + m];
    int lr = wv*16 + qd*4;
    int ib = i0 + lr;
    float sqi[4];
    #pragma unroll
    for (int r=0;r<4;r++) sqi[r] = sq[bb*N_TOK + ib + r];
    #pragma unroll
    for (int r=0;r<4;r++){
        u64 bits = 0;
        #pragma unroll
        for (int ct=0;ct<4;ct++){
            float d2 = sqi[r] + sqj[ct] - 2.0f*acc[ct][r];
            if (d2 < THRESH2) bits |= (u64)1 << (ct*16 + m);
        }
        bits |= shfl_xor_u64(bits, 1);
        bits |= shfl_xor_u64(bits, 2);
        bits |= shfl_xor_u64(bits, 4);
        bits |= shfl_xor_u64(bits, 8);
        if (m == 0){
            Hb[(size_t)(bb*N_TOK + ib + r)*64 + bj] = bits;
            rowW[lr + r] = bits;
        }
    }
    __syncthreads();
    if (bi != bj){   // mirror write (bit-transposed); diagonal tile is its own mirror
        int jj = tid & 63, q = tid >> 6;
        u64 p = 0;
        int ibase = q*16;
        #pragma unroll
        for (int ii=0; ii<16; ii++)
            p |= ((rowW[ibase + ii] >> jj) & 1ull) << (ibase + ii);
        part[tid] = p;
        __syncthreads();
        if (tid < 64){
            u64 wt = part[tid] | part[tid+64] | part[tid+128] | part[tid+192];
            Hb[(size_t)(bb*N_TOK + j0 + tid)*64 + bi] = wt;
        }
    }
}

// K3: TWO-HOP aggregation in ONE pass (numerics proven in round 4):
// Xe_i = Yf_i + nrm_i * sum_{j in N(i)} nrm_j * sum_{k in N(j)} Yf_k
// One wave per output row; H bitwise symmetric; j==i fast path.
// Also accumulates partitioned BN partials.
__global__ __launch_bounds__(256) void k_agg2(const u64* __restrict__ Hb,
                                              const float* __restrict__ Yf,
                                              float* __restrict__ Xe,
                                              float* __restrict__ bnp){
    __shared__ float r1[4][128];
    __shared__ float r2[4][128];
    int tid = threadIdx.x;
    int wv = tid >> 6, lane = tid & 63;
    int row = blockIdx.x * 4 + wv;          // [0, 8192)
    int b = row >> 12;
    const float* Vb = Yf + (size_t)b*N_TOK*C_DIM;
    u64 myw = Hb[(size_t)row*64 + lane];
    int cnt = wave_popc_reduce(myw);
    float nrm_i = (cnt > 0) ? 1.0f/(float)cnt : 0.0f;
    float acc0 = 0.f, acc1 = 0.f;
    u64 nz = __ballot(myw != 0);
    while (nz){
        int wdi = __builtin_ctzll(nz);
        nz &= nz - 1;
        u64 mw = shfl_u64(myw, wdi);
        while (mw){
            int j = wdi*64 + __builtin_ctzll(mw);   // local token in batch
            mw &= mw - 1;
            int jrow = (b << 12) + j;
            u64 jw; float nrm_j;
            if (jrow == row){                        // dominant diagonal case
                jw = myw; nrm_j = nrm_i;
            } else {
                jw = Hb[(size_t)jrow*64 + lane];
                int jc = wave_popc_reduce(jw);
                nrm_j = (jc > 0) ? 1.0f/(float)jc : 0.0f;
            }
            float sub0 = 0.f, sub1 = 0.f;
            u64 jnz = __ballot(jw != 0);
            while (jnz){
                int w2 = __builtin_ctzll(jnz);
                jnz &= jnz - 1;
                u64 m2 = shfl_u64(jw, w2);
                while (m2){
                    int kk = w2*64 + __builtin_ctzll(m2);
                    m2 &= m2 - 1;
                    sub0 += Vb[(size_t)kk*C_DIM + lane];
                    sub1 += Vb[(size_t)kk*C_DIM + lane + 64];
                }
            }
            acc0 += nrm_j * sub0;
            acc1 += nrm_j * sub1;
        }
    }
    size_t o = (size_t)row*C_DIM;
    float xe0 = Yf[o + lane]      + nrm_i*acc0;
    float xe1 = Yf[o + lane + 64] + nrm_i*acc1;
    Xe[o + lane]      = xe0;
    Xe[o + lane + 64] = xe1;
    r1[wv][lane]      = xe0;
    r1[wv][lane + 64] = xe1;
    r2[wv][lane]      = xe0*xe0;
    r2[wv][lane + 64] = xe1*xe1;
    __syncthreads();
    if (tid < 128){
        float s1 = r1[0][tid]+r1[1][tid]+r1[2][tid]+r1[3][tid];
        float s2 = r2[0][tid]+r2[1][tid]+r2[2][tid]+r2[3][tid];
        int prt = blockIdx.x & 7;
        atomicAdd(&bnp[prt*256 + tid],       s1);
        atomicAdd(&bnp[prt*256 + 128 + tid], s2);
    }
}

// K4: BN affine + SiLU + transpose back to [B,C,N], fp32 out.
__global__ __launch_bounds__(256) void k_out(const float* __restrict__ Xe,
                                             const float* __restrict__ bnp,
                                             const float* __restrict__ gamma,
                                             const float* __restrict__ beta,
                                             float* __restrict__ out){
    __shared__ float tile[32][33];
    int tx = threadIdx.x, ty = threadIdx.y;
    int n0 = blockIdx.x*32, c0 = blockIdx.y*32, b = blockIdx.z;
    int c = c0 + tx;
    float s1 = 0.f, s2 = 0.f;
    #pragma unroll
    for (int p=0;p<8;p++){
        s1 += bnp[p*256 + c];
        s2 += bnp[p*256 + 128 + c];
    }
    float inv = 1.0f / (float)NTOT;
    float mean = s1 * inv;
    float var  = s2*inv - mean*mean;
    float scale = gamma[c] * rsqrtf(var + 1e-5f);
    float shift = beta[c] - mean*scale;
    #pragma unroll
    for (int k=0;k<4;k++){
        int nl = ty + 8*k;
        float v = Xe[(size_t)(b*N_TOK + n0 + nl)*C_DIM + c];
        v = scale*v + shift;
        float sg = 1.0f/(1.0f + __expf(-v));
        tile[tx][nl] = v * sg;
    }
    __syncthreads();
    #pragma unroll
    for (int k=0;k<4;k++){
        int cl = ty + 8*k;
        out[(size_t)(b*C_DIM + c0 + cl)*N_TOK + n0 + tx] = tile[cl][tx];
    }
}

extern "C" void kernel_launch(void* const* d_in, const int* in_sizes, int n_in,
                              void* d_out, int out_size, void* d_ws, size_t ws_size,
                              hipStream_t stream){
    if (ws_size < WS_NEED) return;
    const float* x     = (const float*)d_in[0];
    const float* W     = (const float*)d_in[1];
    const float* bfc   = (const float*)d_in[2];
    const float* gamma = (const float*)d_in[3];
    const float* beta  = (const float*)d_in[4];
    char* ws = (char*)d_ws;
    ushort_t* Xf = (ushort_t*)(ws + XF_OFF);
    float*    Yf = (float*)(ws + YF_OFF);
    float*    Xe = (float*)(ws + XE_OFF);
    float*    sqp= (float*)(ws + SQ_OFF);
    float*    bnp= (float*)(ws + BN_OFF);
    u64*      Hb = (u64*)(ws + HB_OFF);
    float*    outp = (float*)d_out;

    k_fc    <<<dim3(128,2),  dim3(256),   0, stream>>>(x, W, bfc, Xf, Yf, sqp, bnp);
    k_gram64<<<dim3(2080,2), dim3(256),   0, stream>>>(Xf, sqp, Hb);
    k_agg2  <<<dim3(2048),   dim3(256),   0, stream>>>(Hb, Yf, Xe, bnp);
    k_out   <<<dim3(128,4,2),dim3(32,8),  0, stream>>>(Xe, bnp, gamma, beta, outp);
}